// Round 1
// baseline (63.425 us; speedup 1.0000x reference)
//
#include <hip/hip_runtime.h>

// GHM-C loss, one-pass formulation:
//   q = (c==t) ? -p : p;  g = sigmoid(q);  bce = softplus(q)
//   bin = min(int(g*10), 9)
//   S[bin] += w*bce ; cnt[bin]++ ; sumw += w   (per-row w, C=8 elems/row)
//   loss = ( sum_b S[b] * (tot/cnt[b]) ) / n_nonempty / (8*sum_row w)

#define NROWS 4194304
#define NCLS 8
#define BINS 10

constexpr int BLOCK = 256;
constexpr int MAXGRID = 2048;
// per-block ws slot: 32 dwords (128 B): f32 [0..9]=S, [10]=sumw ; u32 [16..25]=cnt

__global__ __launch_bounds__(BLOCK) void ghm_main(
    const float* __restrict__ pred, const int* __restrict__ target,
    const float* __restrict__ weight, float* __restrict__ wsF,
    unsigned int* __restrict__ wsU)
{
    __shared__ float wlds[NCLS];
    if (threadIdx.x < NCLS) wlds[threadIdx.x] = weight[threadIdx.x];
    __syncthreads();

    float accS[BINS];
#pragma unroll
    for (int i = 0; i < BINS; ++i) accS[i] = 0.0f;
    unsigned int cnt[BINS];
#pragma unroll
    for (int i = 0; i < BINS; ++i) cnt[i] = 0u;
    float sumw = 0.0f;

    const int stride = gridDim.x * BLOCK;
    const int tid = blockIdx.x * BLOCK + threadIdx.x;

#pragma unroll 2
    for (int r = tid; r < NROWS; r += stride) {
        const float4 p0 = reinterpret_cast<const float4*>(pred)[2 * r + 0];
        const float4 p1 = reinterpret_cast<const float4*>(pred)[2 * r + 1];
        const int   t  = target[r];
        const float w  = wlds[t];
        sumw += w;
        float pv[NCLS] = {p0.x, p0.y, p0.z, p0.w, p1.x, p1.y, p1.z, p1.w};
#pragma unroll
        for (int c = 0; c < NCLS; ++c) {
            const float p = pv[c];
            const float q = (c == t) ? -p : p;
            const float a = __builtin_fabsf(q);
            const float e = __expf(-a);               // exp(-|q|)
            const float d = 1.0f + e;
            const float rr = __builtin_amdgcn_rcpf(d);
            const float g = (q >= 0.0f) ? rr : e * rr;  // sigmoid(q), no cancellation
            const float bce = fmaxf(q, 0.0f) + __logf(d); // softplus(q)
            const float v = w * bce;
            int b = (int)(g * 10.0f);
            b = (b > BINS - 1) ? (BINS - 1) : b;
#pragma unroll
            for (int i = 0; i < BINS; ++i) {
                const bool m = (b == i);
                accS[i] += m ? v : 0.0f;
                cnt[i]  += (unsigned int)__popcll(__ballot(m)); // wave-uniform count
            }
        }
    }

    // wave reduction of accS and sumw (cnt is already wave-uniform via ballot)
#pragma unroll
    for (int i = 0; i < BINS; ++i) {
        float x = accS[i];
#pragma unroll
        for (int o = 32; o >= 1; o >>= 1) x += __shfl_xor(x, o, 64);
        accS[i] = x;
    }
    {
        float x = sumw;
#pragma unroll
        for (int o = 32; o >= 1; o >>= 1) x += __shfl_xor(x, o, 64);
        sumw = x;
    }

    __shared__ float        lS[BLOCK / 64][BINS + 1];
    __shared__ unsigned int lC[BLOCK / 64][BINS];
    const int lane = threadIdx.x & 63;
    const int wv   = threadIdx.x >> 6;
    if (lane == 0) {
#pragma unroll
        for (int i = 0; i < BINS; ++i) { lS[wv][i] = accS[i]; lC[wv][i] = cnt[i]; }
        lS[wv][BINS] = sumw;
    }
    __syncthreads();
    if (threadIdx.x == 0) {
#pragma unroll
        for (int i = 0; i < BINS; ++i) {
            wsF[blockIdx.x * 32 + i]      = lS[0][i] + lS[1][i] + lS[2][i] + lS[3][i];
            wsU[blockIdx.x * 32 + 16 + i] = lC[0][i] + lC[1][i] + lC[2][i] + lC[3][i];
        }
        wsF[blockIdx.x * 32 + 10] = lS[0][BINS] + lS[1][BINS] + lS[2][BINS] + lS[3][BINS];
    }
}

__global__ __launch_bounds__(BLOCK) void ghm_final(
    const float* __restrict__ wsF, const unsigned int* __restrict__ wsU,
    float* __restrict__ out, int nblocks)
{
    float S[BINS]; unsigned int cn[BINS]; float sw = 0.0f;
#pragma unroll
    for (int i = 0; i < BINS; ++i) { S[i] = 0.0f; cn[i] = 0u; }

    for (int b = threadIdx.x; b < nblocks; b += BLOCK) {
#pragma unroll
        for (int i = 0; i < BINS; ++i) {
            S[i]  += wsF[b * 32 + i];
            cn[i] += wsU[b * 32 + 16 + i];
        }
        sw += wsF[b * 32 + 10];
    }

#pragma unroll
    for (int i = 0; i < BINS; ++i) {
        float x = S[i]; unsigned int c2 = cn[i];
#pragma unroll
        for (int o = 32; o >= 1; o >>= 1) {
            x  += __shfl_xor(x, o, 64);
            c2 += __shfl_xor(c2, o, 64);
        }
        S[i] = x; cn[i] = c2;
    }
    {
        float x = sw;
#pragma unroll
        for (int o = 32; o >= 1; o >>= 1) x += __shfl_xor(x, o, 64);
        sw = x;
    }

    __shared__ float        lS[4][BINS + 1];
    __shared__ unsigned int lC[4][BINS];
    const int lane = threadIdx.x & 63;
    const int wv   = threadIdx.x >> 6;
    if (lane == 0) {
#pragma unroll
        for (int i = 0; i < BINS; ++i) { lS[wv][i] = S[i]; lC[wv][i] = cn[i]; }
        lS[wv][BINS] = sw;
    }
    __syncthreads();
    if (threadIdx.x == 0) {
        const float tot = 33554432.0f; // N*C
        int nne = 0; float acc = 0.0f;
        const float swt = lS[0][BINS] + lS[1][BINS] + lS[2][BINS] + lS[3][BINS];
#pragma unroll
        for (int i = 0; i < BINS; ++i) {
            const unsigned int c2 = lC[0][i] + lC[1][i] + lC[2][i] + lC[3][i];
            const float s = lS[0][i] + lS[1][i] + lS[2][i] + lS[3][i];
            if (c2 > 0u) { nne++; acc += s * (tot / (float)c2); }
        }
        out[0] = acc / (float)nne / (8.0f * swt);
    }
}

extern "C" void kernel_launch(void* const* d_in, const int* in_sizes, int n_in,
                              void* d_out, int out_size, void* d_ws, size_t ws_size,
                              hipStream_t stream) {
    const float* pred   = (const float*)d_in[0];
    const int*   target = (const int*)d_in[1];
    const float* weight = (const float*)d_in[2];
    float* out = (float*)d_out;

    int blocks = MAXGRID;
    const size_t need = (size_t)MAXGRID * 128u;
    if (ws_size < need) {
        int cap = (int)(ws_size / 128u);
        blocks = cap < 1 ? 1 : (cap > MAXGRID ? MAXGRID : cap);
    }

    ghm_main<<<blocks, BLOCK, 0, stream>>>(pred, target, weight,
                                           (float*)d_ws, (unsigned int*)d_ws);
    ghm_final<<<1, BLOCK, 0, stream>>>((const float*)d_ws, (const unsigned int*)d_ws,
                                       out, blocks);
}